// Round 8
// baseline (314.483 us; speedup 1.0000x reference)
//
#include <hip/hip_runtime.h>

typedef __attribute__((ext_vector_type(8))) short bf16x8;
typedef __attribute__((ext_vector_type(4))) float f32x4;

#define LOG2E 1.4426950408889634f

// CSR binning parameters: bins of 256 dst nodes
#define BINSH 8
#define NBIN 196        // ceil(50000/256)
#define CHUNK 4096      // edges per bin_scatter block
#define K4CAP 6144      // staged edges per bin in csr_build (avg 4096)

__device__ __forceinline__ unsigned bf_rn(float f) {
    unsigned u = __float_as_uint(f);
    u += 0x7fffu + ((u >> 16) & 1u);
    return u >> 16;
}
__device__ __forceinline__ float bf_lo(unsigned u) { return __uint_as_float(u << 16); }
__device__ __forceinline__ float bf_hi(unsigned u) { return __uint_as_float(u & 0xffff0000u); }

// DPP add helpers (VALU pipe, no DS)
template <int CTRL>
__device__ __forceinline__ float dpp_radd(float x) {
    int t = __builtin_amdgcn_update_dpp(0, __float_as_int(x), CTRL, 0xF, 0xF, true);
    return x + __int_as_float(t);
}
// sum across aligned 4-lane group: quad_perm[1,0,3,2] (^1), quad_perm[2,3,0,1] (^2)
__device__ __forceinline__ float sum4(float p) {
    p = dpp_radd<0xB1>(p);
    p = dpp_radd<0x4E>(p);
    return p;
}
// neighbor swap (lane ^ 1) via quad_perm [1,0,3,2]
__device__ __forceinline__ float dpp_swap1(float x) {
    return __int_as_float(__builtin_amdgcn_update_dpp(0, __float_as_int(x), 0xB1, 0xF, 0xF, true));
}

__device__ __forceinline__ float fast_exp2(float x) {
#if __has_builtin(__builtin_amdgcn_exp2f)
    return __builtin_amdgcn_exp2f(x);
#else
    return __expf(x * 0.6931471805599453f);
#endif
}

// ---------------------------------------------------------------------------
// Binned CSR build (2-pass radix on dst; ~40k atomics instead of 1.6M)
// ---------------------------------------------------------------------------

__global__ __launch_bounds__(256) void bin_count(const int* __restrict__ dst,
                                                 int* __restrict__ binCnt, int e) {
    __shared__ int hist[NBIN];
    for (int t = threadIdx.x; t < NBIN; t += 256) hist[t] = 0;
    __syncthreads();
    int base = blockIdx.x * CHUNK;
    int cnt = min(CHUNK, e - base);
    for (int j = threadIdx.x; j < cnt; j += 256)
        atomicAdd(&hist[dst[base + j] >> BINSH], 1);
    __syncthreads();
    for (int t = threadIdx.x; t < NBIN; t += 256)
        if (hist[t]) atomicAdd(&binCnt[t], hist[t]);
}

__global__ void bin_scan(const int* __restrict__ binCnt, int* __restrict__ binBase,
                         int* __restrict__ binCur, int* __restrict__ rowp, int n, int e) {
    int t = threadIdx.x;
    int v = (t < NBIN) ? binCnt[t] : 0;
    int lane = t & 63, w = t >> 6;
    int incl = v;
    for (int off = 1; off < 64; off <<= 1) {
        int tt = __shfl_up(incl, off);
        if (lane >= off) incl += tt;
    }
    __shared__ int wsum[4];
    if (lane == 63) wsum[w] = incl;
    __syncthreads();
    int wpre = 0;
    for (int i = 0; i < w; ++i) wpre += wsum[i];
    int excl = wpre + incl - v;
    if (t < NBIN) { binBase[t] = excl; binCur[t] = excl; }
    if (t == 0) { binBase[NBIN] = e; rowp[n] = e; }
}

__global__ __launch_bounds__(256) void bin_scatter(
    const int* __restrict__ src, const int* __restrict__ dst,
    int* __restrict__ binCur, unsigned* __restrict__ ebin, int e) {
    __shared__ int hist[NBIN];
    __shared__ int seg[NBIN];
    __shared__ int gbase[NBIN];
    __shared__ unsigned pack[CHUNK];
    for (int t = threadIdx.x; t < NBIN; t += 256) hist[t] = 0;
    __syncthreads();
    int base = blockIdx.x * CHUNK;
    int cnt = min(CHUNK, e - base);

    int myb[CHUNK / 256], myr[CHUNK / 256];
    unsigned myw[CHUNK / 256];
    int nmine = 0;
    for (int j = threadIdx.x; j < cnt; j += 256) {
        int d = dst[base + j], s = src[base + j];
        int b = d >> BINSH, dl = d & ((1 << BINSH) - 1);
        int r = atomicAdd(&hist[b], 1);
        myb[nmine] = b; myr[nmine] = r;
        myw[nmine] = ((unsigned)b << 24) | ((unsigned)dl << 16) | (unsigned)s;
        ++nmine;
    }
    __syncthreads();
    if (threadIdx.x == 0) {
        int acc = 0;
        for (int b2 = 0; b2 < NBIN; ++b2) { seg[b2] = acc; acc += hist[b2]; }
    }
    __syncthreads();
    for (int k = 0; k < nmine; ++k)
        pack[seg[myb[k]] + myr[k]] = myw[k];
    __syncthreads();
    if (threadIdx.x < NBIN && hist[threadIdx.x])
        gbase[threadIdx.x] = atomicAdd(&binCur[threadIdx.x], hist[threadIdx.x]);
    __syncthreads();
    for (int j = threadIdx.x; j < cnt; j += 256) {
        unsigned wv = pack[j];
        int b = wv >> 24;
        ebin[gbase[b] + (j - seg[b])] = wv;
    }
}

__global__ __launch_bounds__(256) void csr_build(
    const unsigned* __restrict__ ebin, const int* __restrict__ binBase,
    int* __restrict__ rowp, int* __restrict__ csrc, int n) {
    __shared__ int hist[256];
    __shared__ int seg[256];
    __shared__ unsigned stage[K4CAP];
    int b = blockIdx.x;
    int e0 = binBase[b], e1 = binBase[b + 1];
    int n0 = b << BINSH;
    int nn = min(256, n - n0);
    for (int t = threadIdx.x; t < 256; t += 256) hist[t] = 0;
    __syncthreads();
    for (int i = e0 + threadIdx.x; i < e1; i += 256) {
        unsigned wv = ebin[i];
        atomicAdd(&hist[(wv >> 16) & 255], 1);
        int off = i - e0;
        if (off < K4CAP) stage[off] = wv;
    }
    __syncthreads();
    if (threadIdx.x < 64) {
        int l = threadIdx.x;
        int s = 0, loc[4];
#pragma unroll
        for (int k = 0; k < 4; ++k) { loc[k] = s; s += hist[l * 4 + k]; }
        int incl = s;
        for (int off = 1; off < 64; off <<= 1) {
            int tt = __shfl_up(incl, off);
            if (l >= off) incl += tt;
        }
        int excl = incl - s;
#pragma unroll
        for (int k = 0; k < 4; ++k) seg[l * 4 + k] = excl + loc[k];
    }
    __syncthreads();
    for (int t = threadIdx.x; t < nn; t += 256) rowp[n0 + t] = e0 + seg[t];
    for (int t = threadIdx.x; t < 256; t += 256) hist[t] = seg[t];
    __syncthreads();
    for (int i = e0 + threadIdx.x; i < e1; i += 256) {
        int off = i - e0;
        unsigned wv = (off < K4CAP) ? stage[off] : ebin[i];
        int dl = (wv >> 16) & 255;
        int pos = e0 + atomicAdd(&hist[dl], 1);
        csrc[pos] = (int)(wv & 0xFFFFu);
    }
}

// ---------------------------------------------------------------------------
// Fused fp32->bf16 feature convert + W transpose/convert (one launch)
// ---------------------------------------------------------------------------

__global__ void prep_all(
    const float* __restrict__ x, unsigned short* __restrict__ o, int n4,
    const float* __restrict__ Ws0, const float* __restrict__ Wd0,
    const float* __restrict__ Ws1, const float* __restrict__ Wd1,
    const float* __restrict__ Ws2, const float* __restrict__ Wd2,
    unsigned short* __restrict__ wt0, unsigned short* __restrict__ wt1,
    unsigned short* __restrict__ wt2) {
    int i = blockIdx.x * blockDim.x + threadIdx.x;
    if (i < n4) {
        float4 v = *(const float4*)(x + (size_t)i * 4);
        ushort4 r;
        r.x = (unsigned short)bf_rn(v.x); r.y = (unsigned short)bf_rn(v.y);
        r.z = (unsigned short)bf_rn(v.z); r.w = (unsigned short)bf_rn(v.w);
        *(ushort4*)(o + (size_t)i * 4) = r;
        return;
    }
    int gid = i - n4;
    if (gid < 65536) {
        int l = gid >> 15, loc = gid & 32767;
        int c = loc >> 7, k = loc & 127;
        const float* W = (c < 128) ? (l ? Ws1 : Ws0) : (l ? Wd1 : Wd0);
        int cc = c & 127;
        float v = W[(size_t)k * 128 + cc];
        (l ? wt1 : wt0)[loc] = (unsigned short)bf_rn(v);
    } else if (gid < 65536 + 8192) {
        int loc = gid - 65536;
        int c = loc >> 7, k = loc & 127;
        const float* W = (c < 32) ? Ws2 : Wd2;
        int cc = (c < 32) ? c : c - 32;
        float v = W[(size_t)k * 32 + cc];
        wt2[loc] = (unsigned short)bf_rn(v);
    }
}

// ---------------------------------------------------------------------------
// Zero-LDS MFMA dual GEMM: [fs|fd] = x @ [Ws|Wd] + [bs|bd].
// ---------------------------------------------------------------------------

template <int COLS2>
__global__ __launch_bounds__(256) void gemm_dual2(
    const unsigned short* __restrict__ xb, const unsigned short* __restrict__ wt,
    const float* __restrict__ bs, const float* __restrict__ bd,
    unsigned short* __restrict__ fs, unsigned short* __restrict__ fd,
    int n, int nch) {
    constexpr int C  = COLS2 / 2;
    constexpr int NC = COLS2 / 64;

    const int lane = threadIdx.x & 63;
    const int m = lane & 15, quad = lane >> 4;
    const int gwid = blockIdx.x * 4 + (threadIdx.x >> 6);
    const int nwaves = gridDim.x * 4;
    const int cs = gwid % NC;
    const int cstride = nwaves / NC;

    float biasv[4];
#pragma unroll
    for (int ct = 0; ct < 4; ++ct) {
        int col = cs * 64 + ct * 16 + m;
        biasv[ct] = (col < C) ? bs[col] : bd[col - C];
    }

    for (int chunk = gwid / NC; chunk < nch; chunk += cstride) {
        const size_t r0 = (size_t)chunk * 64;

        f32x4 acc[4][4];
#pragma unroll
        for (int rt = 0; rt < 4; ++rt)
#pragma unroll
            for (int ct = 0; ct < 4; ++ct) acc[rt][ct] = (f32x4){0.f, 0.f, 0.f, 0.f};

#pragma unroll
        for (int ks = 0; ks < 4; ++ks) {
            const int ko = ks * 32 + quad * 8;
            bf16x8 a[4], b[4];
#pragma unroll
            for (int rt = 0; rt < 4; ++rt)
                a[rt] = *(const bf16x8*)(xb + (r0 + rt * 16 + m) * 128 + ko);
#pragma unroll
            for (int ct = 0; ct < 4; ++ct)
                b[ct] = *(const bf16x8*)(wt + (size_t)(cs * 64 + ct * 16 + m) * 128 + ko);
#pragma unroll
            for (int rt = 0; rt < 4; ++rt)
#pragma unroll
                for (int ct = 0; ct < 4; ++ct)
                    acc[rt][ct] = __builtin_amdgcn_mfma_f32_16x16x32_bf16(a[rt], b[ct], acc[rt][ct], 0, 0, 0);
        }

        const int odd = m & 1;
#pragma unroll
        for (int ct = 0; ct < 4; ++ct) {
            int colE = cs * 64 + ct * 16 + (m & ~1);
            unsigned short* ptr = (colE < C) ? fs : fd;
            int cc = (colE < C) ? colE : colE - C;
#pragma unroll
            for (int rt = 0; rt < 4; ++rt) {
                float v0 = acc[rt][ct][0] + biasv[ct];
                float v1 = acc[rt][ct][1] + biasv[ct];
                float v2 = acc[rt][ct][2] + biasv[ct];
                float v3 = acc[rt][ct][3] + biasv[ct];
                float s0 = dpp_swap1(v0), s1 = dpp_swap1(v1);
                float s2 = dpp_swap1(v2), s3 = dpp_swap1(v3);
                float aLo = odd ? s2 : v0, aHi = odd ? v2 : s0;
                float bLo = odd ? s3 : v1, bHi = odd ? v3 : s1;
                int rowA = (int)r0 + rt * 16 + quad * 4 + (odd ? 2 : 0);
                unsigned pa = (bf_rn(aHi) << 16) | bf_rn(aLo);
                unsigned pb = (bf_rn(bHi) << 16) | bf_rn(bLo);
                if (rowA < n)     *(unsigned*)(ptr + (size_t)rowA * C + cc)       = pa;
                if (rowA + 1 < n) *(unsigned*)(ptr + ((size_t)rowA + 1) * C + cc) = pb;
            }
        }
    }
}

// ---------------------------------------------------------------------------
// GATv2 aggregation. conv128: 4 edges/wave (16 lanes = 8 feats/lane each);
// conv32: 16 edges/wave (4 lanes = 8 feats/lane each). sum4 DPP reduction.
// ---------------------------------------------------------------------------

#define UNPK8(u, arr)                                               \
    arr[0] = bf_lo((u).x); arr[1] = bf_hi((u).x);                   \
    arr[2] = bf_lo((u).y); arr[3] = bf_hi((u).y);                   \
    arr[4] = bf_lo((u).z); arr[5] = bf_hi((u).z);                   \
    arr[6] = bf_lo((u).w); arr[7] = bf_hi((u).w);

// per-edge math: 8 feats/lane, 4-lane head groups. mval masks ex.
#define EDGE_BODY8(u, mval)                                         \
    do {                                                            \
        float x[8];                                                 \
        UNPK8(u, x)                                                 \
        float t0 = x[0] + fdv[0];                                   \
        float p = a06[0] * t0;                                      \
        p = fmaf(a04[0], fabsf(t0), p);                             \
        _Pragma("unroll")                                           \
        for (int k = 1; k < 8; ++k) {                               \
            float t = x[k] + fdv[k];                                \
            p = fmaf(a06[k], t, p);                                 \
            p = fmaf(a04[k], fabsf(t), p);                          \
        }                                                           \
        p = sum4(p);                                                \
        float ex = fast_exp2(p) * (mval);                           \
        denom += ex;                                                \
        _Pragma("unroll")                                           \
        for (int k = 0; k < 8; ++k) acc[k] = fmaf(ex, x[k], acc[k]);\
    } while (0)

__global__ __launch_bounds__(256) void conv128(
    const unsigned short* __restrict__ fs, const unsigned short* __restrict__ fd,
    const float* __restrict__ attn, const int* __restrict__ rowp,
    const int* __restrict__ csrc, unsigned short* __restrict__ out, int n) {
    const int nwaves = gridDim.x * 4;
    const int wid0 = blockIdx.x * 4 + (threadIdx.x >> 6);
    const int lane = threadIdx.x & 63;
    const int quarter = lane >> 4;   // which edge of the 4
    const int q = lane & 15;         // 8-feat chunk [0,16); head = q>>2

    float a06[8], a04[8];
    {
        float4 av0 = *(const float4*)(attn + q * 8);
        float4 av1 = *(const float4*)(attn + q * 8 + 4);
        float avv[8] = {av0.x, av0.y, av0.z, av0.w, av1.x, av1.y, av1.z, av1.w};
#pragma unroll
        for (int k = 0; k < 8; ++k) {
            a06[k] = avv[k] * 0.6f * LOG2E;
            a04[k] = avv[k] * 0.4f * LOG2E;
        }
    }

    for (int wid = wid0; wid < n; wid += nwaves) {
        uint4 ud = *(const uint4*)(fd + (size_t)wid * 128 + q * 8);
        float fdv[8];
        UNPK8(ud, fdv)
        int rs = rowp[wid], re = rowp[wid + 1];
        float acc[8] = {0.f, 0.f, 0.f, 0.f, 0.f, 0.f, 0.f, 0.f};
        float denom = 0.f;

        int i = rs;
        // 8 edges in flight (two 4-edge groups)
        for (; i + 7 < re; i += 8) {
            int sA = csrc[i + quarter];
            int sB = csrc[i + 4 + quarter];
            uint4 uA = *(const uint4*)(fs + ((size_t)sA << 7) + q * 8);
            uint4 uB = *(const uint4*)(fs + ((size_t)sB << 7) + q * 8);
            EDGE_BODY8(uA, 1.0f);
            EDGE_BODY8(uB, 1.0f);
        }
        for (; i + 3 < re; i += 4) {
            int s = csrc[i + quarter];
            uint4 u = *(const uint4*)(fs + ((size_t)s << 7) + q * 8);
            EDGE_BODY8(u, 1.0f);
        }
        if (i < re) {  // masked tail (1-3 edges)
            int idx = i + quarter;
            int s = csrc[min(idx, re - 1)];
            uint4 u = *(const uint4*)(fs + ((size_t)s << 7) + q * 8);
            float mval = (idx < re) ? 1.f : 0.f;
            EDGE_BODY8(u, mval);
        }
        // combine the four quarters
#pragma unroll
        for (int k = 0; k < 8; ++k) {
            acc[k] += __shfl_xor(acc[k], 16);
            acc[k] += __shfl_xor(acc[k], 32);
        }
        denom += __shfl_xor(denom, 16);
        denom += __shfl_xor(denom, 32);
        float inv = (re > rs) ? 1.f / denom : 0.f;
        if (quarter == 0) {
            float r[8];
#pragma unroll
            for (int k = 0; k < 8; ++k) r[k] = fmaxf(acc[k] * inv, 0.f);  // fused ReLU
            uint4 o;
            o.x = (bf_rn(r[1]) << 16) | bf_rn(r[0]);
            o.y = (bf_rn(r[3]) << 16) | bf_rn(r[2]);
            o.z = (bf_rn(r[5]) << 16) | bf_rn(r[4]);
            o.w = (bf_rn(r[7]) << 16) | bf_rn(r[6]);
            *(uint4*)(out + (size_t)wid * 128 + q * 8) = o;
        }
    }
}

// Layer 2: 1 head x 32 feats; 16 edges/wave, 4 lanes (8 feats each) per edge.
__global__ __launch_bounds__(256) void conv32(
    const unsigned short* __restrict__ fs, const unsigned short* __restrict__ fd,
    const float* __restrict__ attn, const int* __restrict__ rowp,
    const int* __restrict__ csrc, float* __restrict__ out, int n) {
    const int nwaves = gridDim.x * 4;
    const int wid0 = blockIdx.x * 4 + (threadIdx.x >> 6);
    const int lane = threadIdx.x & 63;
    const int g = lane >> 2;    // edge slot [0,16)
    const int c = lane & 3;     // 8-feat chunk [0,4)

    float a06[8], a04[8];
    {
        float4 av0 = *(const float4*)(attn + c * 8);
        float4 av1 = *(const float4*)(attn + c * 8 + 4);
        float avv[8] = {av0.x, av0.y, av0.z, av0.w, av1.x, av1.y, av1.z, av1.w};
#pragma unroll
        for (int k = 0; k < 8; ++k) {
            a06[k] = avv[k] * 0.6f * LOG2E;
            a04[k] = avv[k] * 0.4f * LOG2E;
        }
    }

    for (int wid = wid0; wid < n; wid += nwaves) {
        uint4 ud = *(const uint4*)(fd + (size_t)wid * 32 + c * 8);
        float fdv[8];
        UNPK8(ud, fdv)
        int rs = rowp[wid], re = rowp[wid + 1];
        float acc[8] = {0.f, 0.f, 0.f, 0.f, 0.f, 0.f, 0.f, 0.f};
        float denom = 0.f;

        int i = rs;
        for (; i + 15 < re; i += 16) {
            int s = csrc[i + g];
            uint4 u = *(const uint4*)(fs + ((size_t)s << 5) + c * 8);
            EDGE_BODY8(u, 1.0f);
        }
        if (i < re) {  // masked tail group (1-15 edges)
            int idx = i + g;
            int s = csrc[min(idx, re - 1)];
            uint4 u = *(const uint4*)(fs + ((size_t)s << 5) + c * 8);
            float mval = (idx < re) ? 1.f : 0.f;
            EDGE_BODY8(u, mval);
        }
        // combine the 16 edge slots (bits 2..5 of lane)
#pragma unroll
        for (int k = 0; k < 8; ++k) {
            acc[k] += __shfl_xor(acc[k], 4);
            acc[k] += __shfl_xor(acc[k], 8);
            acc[k] += __shfl_xor(acc[k], 16);
            acc[k] += __shfl_xor(acc[k], 32);
        }
        denom += __shfl_xor(denom, 4);
        denom += __shfl_xor(denom, 8);
        denom += __shfl_xor(denom, 16);
        denom += __shfl_xor(denom, 32);
        float inv = (re > rs) ? 1.f / denom : 0.f;
        if (g == 0) {
            float4 o0, o1;
            o0.x = acc[0] * inv; o0.y = acc[1] * inv;
            o0.z = acc[2] * inv; o0.w = acc[3] * inv;
            o1.x = acc[4] * inv; o1.y = acc[5] * inv;
            o1.z = acc[6] * inv; o1.w = acc[7] * inv;
            *(float4*)(out + (size_t)wid * 32 + c * 8)     = o0;
            *(float4*)(out + (size_t)wid * 32 + c * 8 + 4) = o1;
        }
    }
}

// ---------------------------------------------------------------------------

extern "C" void kernel_launch(void* const* d_in, const int* in_sizes, int n_in,
                              void* d_out, int out_size, void* d_ws, size_t ws_size,
                              hipStream_t stream) {
    const float* feats = (const float*)d_in[0];
    const int*   src   = (const int*)d_in[1];
    const int*   dst   = (const int*)d_in[2];
    const float* Ws0 = (const float*)d_in[3],  *bs0 = (const float*)d_in[4];
    const float* Wd0 = (const float*)d_in[5],  *bd0 = (const float*)d_in[6];
    const float* a0  = (const float*)d_in[7];
    const float* Ws1 = (const float*)d_in[8],  *bs1 = (const float*)d_in[9];
    const float* Wd1 = (const float*)d_in[10], *bd1 = (const float*)d_in[11];
    const float* a1  = (const float*)d_in[12];
    const float* Ws2 = (const float*)d_in[13], *bs2 = (const float*)d_in[14];
    const float* Wd2 = (const float*)d_in[15], *bd2 = (const float*)d_in[16];
    const float* a2  = (const float*)d_in[17];

    const int N = in_sizes[0] / 128;  // 50000
    const int E = in_sizes[1];        // 800000
    const int nch = (N + 63) / 64;
    const int NPAD = nch * 64;

    char* ws = (char*)d_ws;
    const size_t featB = (size_t)NPAD * 128 * 2;
    unsigned short* xb  = (unsigned short*)(ws);
    unsigned short* hb  = (unsigned short*)(ws + featB);
    unsigned short* fsb = (unsigned short*)(ws + 2 * featB);
    unsigned short* fdb = (unsigned short*)(ws + 3 * featB);
    char* p = ws + 4 * featB;
    unsigned short* wt0 = (unsigned short*)p; p += 256 * 128 * 2;
    unsigned short* wt1 = (unsigned short*)p; p += 256 * 128 * 2;
    unsigned short* wt2 = (unsigned short*)p; p += 64 * 128 * 2;
    int* rowp    = (int*)p;      p += ((size_t)(N + 1) * 4 + 255) / 256 * 256;
    int* binCnt  = (int*)p;      p += (NBIN * 4 + 255) / 256 * 256;
    int* binBase = (int*)p;      p += ((NBIN + 1) * 4 + 255) / 256 * 256;
    int* binCur  = (int*)p;      p += (NBIN * 4 + 255) / 256 * 256;
    unsigned* ebin = (unsigned*)p; p += (size_t)E * 4;
    int* csrc    = (int*)p;

    const int nchunks = (E + CHUNK - 1) / CHUNK;

    // ---- binned CSR build ----
    hipMemsetAsync(binCnt, 0, NBIN * 4, stream);
    bin_count<<<nchunks, 256, 0, stream>>>(dst, binCnt, E);
    bin_scan<<<1, 256, 0, stream>>>(binCnt, binBase, binCur, rowp, N, E);
    bin_scatter<<<nchunks, 256, 0, stream>>>(src, dst, binCur, ebin, E);
    csr_build<<<NBIN, 256, 0, stream>>>(ebin, binBase, rowp, csrc, N);

    // ---- fused bf16 conversions (features + all weight transposes) ----
    const int n4 = N * 128 / 4;
    const int prepTot = n4 + 65536 + 8192;
    prep_all<<<(prepTot + 255) / 256, 256, 0, stream>>>(
        feats, xb, n4, Ws0, Wd0, Ws1, Wd1, Ws2, Wd2, wt0, wt1, wt2);

    const int g256 = nch;
    const int g64  = (nch + 3) / 4;
    const int convGrid = 2048;  // 8192 persistent waves

    // ---- layer 0 ----
    gemm_dual2<256><<<g256, 256, 0, stream>>>(xb, wt0, bs0, bd0, fsb, fdb, N, nch);
    conv128<<<convGrid, 256, 0, stream>>>(fsb, fdb, a0, rowp, csrc, hb, N);
    // ---- layer 1 ----
    gemm_dual2<256><<<g256, 256, 0, stream>>>(hb, wt1, bs1, bd1, fsb, fdb, N, nch);
    conv128<<<convGrid, 256, 0, stream>>>(fsb, fdb, a1, rowp, csrc, hb, N);
    // ---- layer 2 ----
    gemm_dual2<64><<<g64, 256, 0, stream>>>(hb, wt2, bs2, bd2, fsb, fdb, N, nch);
    conv32<<<convGrid, 256, 0, stream>>>(fsb, fdb, a2, rowp, csrc, (float*)d_out, N);
}

// Round 9
// 308.892 us; speedup vs baseline: 1.0181x; 1.0181x over previous
//
#include <hip/hip_runtime.h>

typedef __attribute__((ext_vector_type(8))) short bf16x8;
typedef __attribute__((ext_vector_type(4))) float f32x4;

#define LOG2E 1.4426950408889634f

// CSR binning parameters: bins of 256 dst nodes
#define BINSH 8
#define NBIN 196        // ceil(50000/256)
#define CHUNK 4096      // edges per bin_scatter block
#define K4CAP 6144      // staged edges per bin in csr_build (avg 4096)

__device__ __forceinline__ unsigned bf_rn(float f) {
    unsigned u = __float_as_uint(f);
    u += 0x7fffu + ((u >> 16) & 1u);
    return u >> 16;
}
__device__ __forceinline__ float bf_lo(unsigned u) { return __uint_as_float(u << 16); }
__device__ __forceinline__ float bf_hi(unsigned u) { return __uint_as_float(u & 0xffff0000u); }

// DPP add helpers (VALU pipe, no DS)
template <int CTRL>
__device__ __forceinline__ float dpp_radd(float x) {
    int t = __builtin_amdgcn_update_dpp(0, __float_as_int(x), CTRL, 0xF, 0xF, true);
    return x + __int_as_float(t);
}
// sum across aligned 8-lane group:
// row_half_mirror, quad_perm[3,2,1,0], quad_perm[1,0,3,2]
__device__ __forceinline__ float sum8(float p) {
    p = dpp_radd<0x141>(p);
    p = dpp_radd<0x1B>(p);
    p = dpp_radd<0xB1>(p);
    return p;
}
// neighbor swap (lane ^ 1) via quad_perm [1,0,3,2]
__device__ __forceinline__ float dpp_swap1(float x) {
    return __int_as_float(__builtin_amdgcn_update_dpp(0, __float_as_int(x), 0xB1, 0xF, 0xF, true));
}

__device__ __forceinline__ float fast_exp2(float x) {
#if __has_builtin(__builtin_amdgcn_exp2f)
    return __builtin_amdgcn_exp2f(x);
#else
    return __expf(x * 0.6931471805599453f);
#endif
}

// ---------------------------------------------------------------------------
// Binned CSR build (2-pass radix on dst; ~40k atomics instead of 1.6M)
// ---------------------------------------------------------------------------

__global__ __launch_bounds__(256) void bin_count(const int* __restrict__ dst,
                                                 int* __restrict__ binCnt, int e) {
    __shared__ int hist[NBIN];
    for (int t = threadIdx.x; t < NBIN; t += 256) hist[t] = 0;
    __syncthreads();
    int base = blockIdx.x * CHUNK;
    int cnt = min(CHUNK, e - base);
    for (int j = threadIdx.x; j < cnt; j += 256)
        atomicAdd(&hist[dst[base + j] >> BINSH], 1);
    __syncthreads();
    for (int t = threadIdx.x; t < NBIN; t += 256)
        if (hist[t]) atomicAdd(&binCnt[t], hist[t]);
}

__global__ void bin_scan(const int* __restrict__ binCnt, int* __restrict__ binBase,
                         int* __restrict__ binCur, int* __restrict__ rowp, int n, int e) {
    int t = threadIdx.x;
    int v = (t < NBIN) ? binCnt[t] : 0;
    int lane = t & 63, w = t >> 6;
    int incl = v;
    for (int off = 1; off < 64; off <<= 1) {
        int tt = __shfl_up(incl, off);
        if (lane >= off) incl += tt;
    }
    __shared__ int wsum[4];
    if (lane == 63) wsum[w] = incl;
    __syncthreads();
    int wpre = 0;
    for (int i = 0; i < w; ++i) wpre += wsum[i];
    int excl = wpre + incl - v;
    if (t < NBIN) { binBase[t] = excl; binCur[t] = excl; }
    if (t == 0) { binBase[NBIN] = e; rowp[n] = e; }
}

__global__ __launch_bounds__(256) void bin_scatter(
    const int* __restrict__ src, const int* __restrict__ dst,
    int* __restrict__ binCur, unsigned* __restrict__ ebin, int e) {
    __shared__ int hist[NBIN];
    __shared__ int seg[NBIN];
    __shared__ int gbase[NBIN];
    __shared__ unsigned pack[CHUNK];
    for (int t = threadIdx.x; t < NBIN; t += 256) hist[t] = 0;
    __syncthreads();
    int base = blockIdx.x * CHUNK;
    int cnt = min(CHUNK, e - base);

    int myb[CHUNK / 256], myr[CHUNK / 256];
    unsigned myw[CHUNK / 256];
    int nmine = 0;
    for (int j = threadIdx.x; j < cnt; j += 256) {
        int d = dst[base + j], s = src[base + j];
        int b = d >> BINSH, dl = d & ((1 << BINSH) - 1);
        int r = atomicAdd(&hist[b], 1);
        myb[nmine] = b; myr[nmine] = r;
        myw[nmine] = ((unsigned)b << 24) | ((unsigned)dl << 16) | (unsigned)s;
        ++nmine;
    }
    __syncthreads();
    if (threadIdx.x == 0) {
        int acc = 0;
        for (int b2 = 0; b2 < NBIN; ++b2) { seg[b2] = acc; acc += hist[b2]; }
    }
    __syncthreads();
    for (int k = 0; k < nmine; ++k)
        pack[seg[myb[k]] + myr[k]] = myw[k];
    __syncthreads();
    if (threadIdx.x < NBIN && hist[threadIdx.x])
        gbase[threadIdx.x] = atomicAdd(&binCur[threadIdx.x], hist[threadIdx.x]);
    __syncthreads();
    for (int j = threadIdx.x; j < cnt; j += 256) {
        unsigned wv = pack[j];
        int b = wv >> 24;
        ebin[gbase[b] + (j - seg[b])] = wv;
    }
}

__global__ __launch_bounds__(256) void csr_build(
    const unsigned* __restrict__ ebin, const int* __restrict__ binBase,
    int* __restrict__ rowp, int* __restrict__ csrc, int n) {
    __shared__ int hist[256];
    __shared__ int seg[256];
    __shared__ unsigned stage[K4CAP];
    int b = blockIdx.x;
    int e0 = binBase[b], e1 = binBase[b + 1];
    int n0 = b << BINSH;
    int nn = min(256, n - n0);
    for (int t = threadIdx.x; t < 256; t += 256) hist[t] = 0;
    __syncthreads();
    for (int i = e0 + threadIdx.x; i < e1; i += 256) {
        unsigned wv = ebin[i];
        atomicAdd(&hist[(wv >> 16) & 255], 1);
        int off = i - e0;
        if (off < K4CAP) stage[off] = wv;
    }
    __syncthreads();
    if (threadIdx.x < 64) {
        int l = threadIdx.x;
        int s = 0, loc[4];
#pragma unroll
        for (int k = 0; k < 4; ++k) { loc[k] = s; s += hist[l * 4 + k]; }
        int incl = s;
        for (int off = 1; off < 64; off <<= 1) {
            int tt = __shfl_up(incl, off);
            if (l >= off) incl += tt;
        }
        int excl = incl - s;
#pragma unroll
        for (int k = 0; k < 4; ++k) seg[l * 4 + k] = excl + loc[k];
    }
    __syncthreads();
    for (int t = threadIdx.x; t < nn; t += 256) rowp[n0 + t] = e0 + seg[t];
    for (int t = threadIdx.x; t < 256; t += 256) hist[t] = seg[t];
    __syncthreads();
    for (int i = e0 + threadIdx.x; i < e1; i += 256) {
        int off = i - e0;
        unsigned wv = (off < K4CAP) ? stage[off] : ebin[i];
        int dl = (wv >> 16) & 255;
        int pos = e0 + atomicAdd(&hist[dl], 1);
        csrc[pos] = (int)(wv & 0xFFFFu);
    }
}

// ---------------------------------------------------------------------------
// Fused fp32->bf16 feature convert + W transpose/convert (one launch)
// ---------------------------------------------------------------------------

__global__ void prep_all(
    const float* __restrict__ x, unsigned short* __restrict__ o, int n4,
    const float* __restrict__ Ws0, const float* __restrict__ Wd0,
    const float* __restrict__ Ws1, const float* __restrict__ Wd1,
    const float* __restrict__ Ws2, const float* __restrict__ Wd2,
    unsigned short* __restrict__ wt0, unsigned short* __restrict__ wt1,
    unsigned short* __restrict__ wt2) {
    int i = blockIdx.x * blockDim.x + threadIdx.x;
    if (i < n4) {
        float4 v = *(const float4*)(x + (size_t)i * 4);
        ushort4 r;
        r.x = (unsigned short)bf_rn(v.x); r.y = (unsigned short)bf_rn(v.y);
        r.z = (unsigned short)bf_rn(v.z); r.w = (unsigned short)bf_rn(v.w);
        *(ushort4*)(o + (size_t)i * 4) = r;
        return;
    }
    int gid = i - n4;
    if (gid < 65536) {
        int l = gid >> 15, loc = gid & 32767;
        int c = loc >> 7, k = loc & 127;
        const float* W = (c < 128) ? (l ? Ws1 : Ws0) : (l ? Wd1 : Wd0);
        int cc = c & 127;
        float v = W[(size_t)k * 128 + cc];
        (l ? wt1 : wt0)[loc] = (unsigned short)bf_rn(v);
    } else if (gid < 65536 + 8192) {
        int loc = gid - 65536;
        int c = loc >> 7, k = loc & 127;
        const float* W = (c < 32) ? Ws2 : Wd2;
        int cc = (c < 32) ? c : c - 32;
        float v = W[(size_t)k * 32 + cc];
        wt2[loc] = (unsigned short)bf_rn(v);
    }
}

// ---------------------------------------------------------------------------
// Zero-LDS MFMA dual GEMM: [fs|fd] = x @ [Ws|Wd] + [bs|bd].
// ---------------------------------------------------------------------------

template <int COLS2>
__global__ __launch_bounds__(256) void gemm_dual2(
    const unsigned short* __restrict__ xb, const unsigned short* __restrict__ wt,
    const float* __restrict__ bs, const float* __restrict__ bd,
    unsigned short* __restrict__ fs, unsigned short* __restrict__ fd,
    int n, int nch) {
    constexpr int C  = COLS2 / 2;
    constexpr int NC = COLS2 / 64;

    const int lane = threadIdx.x & 63;
    const int m = lane & 15, quad = lane >> 4;
    const int gwid = blockIdx.x * 4 + (threadIdx.x >> 6);
    const int nwaves = gridDim.x * 4;
    const int cs = gwid % NC;
    const int cstride = nwaves / NC;

    float biasv[4];
#pragma unroll
    for (int ct = 0; ct < 4; ++ct) {
        int col = cs * 64 + ct * 16 + m;
        biasv[ct] = (col < C) ? bs[col] : bd[col - C];
    }

    for (int chunk = gwid / NC; chunk < nch; chunk += cstride) {
        const size_t r0 = (size_t)chunk * 64;

        f32x4 acc[4][4];
#pragma unroll
        for (int rt = 0; rt < 4; ++rt)
#pragma unroll
            for (int ct = 0; ct < 4; ++ct) acc[rt][ct] = (f32x4){0.f, 0.f, 0.f, 0.f};

#pragma unroll
        for (int ks = 0; ks < 4; ++ks) {
            const int ko = ks * 32 + quad * 8;
            bf16x8 a[4], b[4];
#pragma unroll
            for (int rt = 0; rt < 4; ++rt)
                a[rt] = *(const bf16x8*)(xb + (r0 + rt * 16 + m) * 128 + ko);
#pragma unroll
            for (int ct = 0; ct < 4; ++ct)
                b[ct] = *(const bf16x8*)(wt + (size_t)(cs * 64 + ct * 16 + m) * 128 + ko);
#pragma unroll
            for (int rt = 0; rt < 4; ++rt)
#pragma unroll
                for (int ct = 0; ct < 4; ++ct)
                    acc[rt][ct] = __builtin_amdgcn_mfma_f32_16x16x32_bf16(a[rt], b[ct], acc[rt][ct], 0, 0, 0);
        }

        const int odd = m & 1;
#pragma unroll
        for (int ct = 0; ct < 4; ++ct) {
            int colE = cs * 64 + ct * 16 + (m & ~1);
            unsigned short* ptr = (colE < C) ? fs : fd;
            int cc = (colE < C) ? colE : colE - C;
#pragma unroll
            for (int rt = 0; rt < 4; ++rt) {
                float v0 = acc[rt][ct][0] + biasv[ct];
                float v1 = acc[rt][ct][1] + biasv[ct];
                float v2 = acc[rt][ct][2] + biasv[ct];
                float v3 = acc[rt][ct][3] + biasv[ct];
                float s0 = dpp_swap1(v0), s1 = dpp_swap1(v1);
                float s2 = dpp_swap1(v2), s3 = dpp_swap1(v3);
                float aLo = odd ? s2 : v0, aHi = odd ? v2 : s0;
                float bLo = odd ? s3 : v1, bHi = odd ? v3 : s1;
                int rowA = (int)r0 + rt * 16 + quad * 4 + (odd ? 2 : 0);
                unsigned pa = (bf_rn(aHi) << 16) | bf_rn(aLo);
                unsigned pb = (bf_rn(bHi) << 16) | bf_rn(bLo);
                if (rowA < n)     *(unsigned*)(ptr + (size_t)rowA * C + cc)       = pa;
                if (rowA + 1 < n) *(unsigned*)(ptr + ((size_t)rowA + 1) * C + cc) = pb;
            }
        }
    }
}

// ---------------------------------------------------------------------------
// GATv2 aggregation (round-7 layout + deeper MLP).
// conv128: 2 edges/wave (32 lanes, 4 feats/lane), 8 edges in flight.
// conv32: 8 edges/wave (8 lanes, 4 feats/lane), 16 edges in flight.
// ---------------------------------------------------------------------------

// per-edge math: 4 feats/lane, 8-lane head groups. mval masks ex.
#define EDGE_BODY(u, mval)                                          \
    do {                                                            \
        float x0 = bf_lo((u).x), x1 = bf_hi((u).x);                 \
        float x2 = bf_lo((u).y), x3 = bf_hi((u).y);                 \
        float t0 = x0 + fd0, t1 = x1 + fd1;                         \
        float t2 = x2 + fd2, t3 = x3 + fd3;                         \
        float p = a060 * t0;                                        \
        p = fmaf(a040, fabsf(t0), p);                               \
        p = fmaf(a061, t1, p); p = fmaf(a041, fabsf(t1), p);        \
        p = fmaf(a062, t2, p); p = fmaf(a042, fabsf(t2), p);        \
        p = fmaf(a063, t3, p); p = fmaf(a043, fabsf(t3), p);        \
        p = sum8(p);                                                \
        float ex = fast_exp2(p) * (mval);                           \
        denom += ex;                                                \
        acc0 = fmaf(ex, x0, acc0); acc1 = fmaf(ex, x1, acc1);       \
        acc2 = fmaf(ex, x2, acc2); acc3 = fmaf(ex, x3, acc3);       \
    } while (0)

__global__ __launch_bounds__(256) void conv128(
    const unsigned short* __restrict__ fs, const unsigned short* __restrict__ fd,
    const float* __restrict__ attn, const int* __restrict__ rowp,
    const int* __restrict__ csrc, unsigned short* __restrict__ out, int n) {
    const int nwaves = gridDim.x * 4;
    const int wid0 = blockIdx.x * 4 + (threadIdx.x >> 6);
    const int lane = threadIdx.x & 63;
    const int half = lane >> 5;     // which edge of the pair
    const int q = lane & 31;        // 4-feat chunk [0,32); head = q>>3

    float4 av = *(const float4*)(attn + q * 4);
    const float a060 = av.x * 0.6f * LOG2E, a040 = av.x * 0.4f * LOG2E;
    const float a061 = av.y * 0.6f * LOG2E, a041 = av.y * 0.4f * LOG2E;
    const float a062 = av.z * 0.6f * LOG2E, a042 = av.z * 0.4f * LOG2E;
    const float a063 = av.w * 0.6f * LOG2E, a043 = av.w * 0.4f * LOG2E;

    for (int wid = wid0; wid < n; wid += nwaves) {
        uint2 ud = *(const uint2*)(fd + (size_t)wid * 128 + q * 4);
        float fd0 = bf_lo(ud.x), fd1 = bf_hi(ud.x);
        float fd2 = bf_lo(ud.y), fd3 = bf_hi(ud.y);
        int rs = rowp[wid], re = rowp[wid + 1];
        float acc0 = 0.f, acc1 = 0.f, acc2 = 0.f, acc3 = 0.f, denom = 0.f;

        int i = rs;
        // 8 edges in flight: 4 independent uint2 gathers queued per lane
        for (; i + 7 < re; i += 8) {
            int sA = csrc[i + half];
            int sB = csrc[i + 2 + half];
            int sC = csrc[i + 4 + half];
            int sD = csrc[i + 6 + half];
            uint2 uA = *(const uint2*)(fs + ((size_t)sA << 7) + q * 4);
            uint2 uB = *(const uint2*)(fs + ((size_t)sB << 7) + q * 4);
            uint2 uC = *(const uint2*)(fs + ((size_t)sC << 7) + q * 4);
            uint2 uD = *(const uint2*)(fs + ((size_t)sD << 7) + q * 4);
            EDGE_BODY(uA, 1.0f);
            EDGE_BODY(uB, 1.0f);
            EDGE_BODY(uC, 1.0f);
            EDGE_BODY(uD, 1.0f);
        }
        for (; i + 1 < re; i += 2) {
            int s = csrc[i + half];
            uint2 u = *(const uint2*)(fs + ((size_t)s << 7) + q * 4);
            EDGE_BODY(u, 1.0f);
        }
        if (i < re) {  // odd tail: both halves load same edge, half 1 masked
            int s = csrc[i];
            uint2 u = *(const uint2*)(fs + ((size_t)s << 7) + q * 4);
            float mval = half ? 0.f : 1.f;
            EDGE_BODY(u, mval);
        }
        // combine the two halves
        acc0 += __shfl_xor(acc0, 32); acc1 += __shfl_xor(acc1, 32);
        acc2 += __shfl_xor(acc2, 32); acc3 += __shfl_xor(acc3, 32);
        denom += __shfl_xor(denom, 32);
        float inv = (re > rs) ? 1.f / denom : 0.f;
        float r0 = fmaxf(acc0 * inv, 0.f), r1 = fmaxf(acc1 * inv, 0.f);
        float r2 = fmaxf(acc2 * inv, 0.f), r3 = fmaxf(acc3 * inv, 0.f);
        if (half == 0) {
            uint2 o;
            o.x = (bf_rn(r1) << 16) | bf_rn(r0);
            o.y = (bf_rn(r3) << 16) | bf_rn(r2);
            ((uint2*)(out + (size_t)wid * 128))[q] = o;
        }
    }
}

// Layer 2: 1 head x 32 feats; 8 edges/wave, 8 lanes (4 feats each) per edge;
// 2 groups in flight (16 edges).
__global__ __launch_bounds__(256) void conv32(
    const unsigned short* __restrict__ fs, const unsigned short* __restrict__ fd,
    const float* __restrict__ attn, const int* __restrict__ rowp,
    const int* __restrict__ csrc, float* __restrict__ out, int n) {
    const int nwaves = gridDim.x * 4;
    const int wid0 = blockIdx.x * 4 + (threadIdx.x >> 6);
    const int lane = threadIdx.x & 63;
    const int g = lane >> 3;    // edge slot [0,8)
    const int c = lane & 7;     // 4-feat chunk [0,8)

    float4 av = *(const float4*)(attn + c * 4);
    const float a060 = av.x * 0.6f * LOG2E, a040 = av.x * 0.4f * LOG2E;
    const float a061 = av.y * 0.6f * LOG2E, a041 = av.y * 0.4f * LOG2E;
    const float a062 = av.z * 0.6f * LOG2E, a042 = av.z * 0.4f * LOG2E;
    const float a063 = av.w * 0.6f * LOG2E, a043 = av.w * 0.4f * LOG2E;

    for (int wid = wid0; wid < n; wid += nwaves) {
        uint2 ud = *(const uint2*)(fd + (size_t)wid * 32 + c * 4);
        float fd0 = bf_lo(ud.x), fd1 = bf_hi(ud.x);
        float fd2 = bf_lo(ud.y), fd3 = bf_hi(ud.y);
        int rs = rowp[wid], re = rowp[wid + 1];
        float acc0 = 0.f, acc1 = 0.f, acc2 = 0.f, acc3 = 0.f, denom = 0.f;

        int i = rs;
        for (; i + 15 < re; i += 16) {  // 16 edges in flight
            int s0 = csrc[i + g];
            int s1 = csrc[i + 8 + g];
            uint2 u0 = *(const uint2*)(fs + ((size_t)s0 << 5) + c * 4);
            uint2 u1 = *(const uint2*)(fs + ((size_t)s1 << 5) + c * 4);
            EDGE_BODY(u0, 1.0f);
            EDGE_BODY(u1, 1.0f);
        }
        for (; i + 7 < re; i += 8) {
            int s = csrc[i + g];
            uint2 u = *(const uint2*)(fs + ((size_t)s << 5) + c * 4);
            EDGE_BODY(u, 1.0f);
        }
        if (i < re) {  // masked tail group
            int idx = i + g;
            int s = csrc[min(idx, re - 1)];
            uint2 u = *(const uint2*)(fs + ((size_t)s << 5) + c * 4);
            float mval = (idx < re) ? 1.f : 0.f;
            EDGE_BODY(u, mval);
        }
        // combine the 8 edge slots: rot8-within-16 (DPP), then xor 16, 32
        acc0 = dpp_radd<0x128>(acc0); acc1 = dpp_radd<0x128>(acc1);
        acc2 = dpp_radd<0x128>(acc2); acc3 = dpp_radd<0x128>(acc3);
        denom = dpp_radd<0x128>(denom);
        acc0 += __shfl_xor(acc0, 16); acc1 += __shfl_xor(acc1, 16);
        acc2 += __shfl_xor(acc2, 16); acc3 += __shfl_xor(acc3, 16);
        denom += __shfl_xor(denom, 16);
        acc0 += __shfl_xor(acc0, 32); acc1 += __shfl_xor(acc1, 32);
        acc2 += __shfl_xor(acc2, 32); acc3 += __shfl_xor(acc3, 32);
        denom += __shfl_xor(denom, 32);
        float inv = (re > rs) ? 1.f / denom : 0.f;
        if (lane < 8) {
            float4 o;
            o.x = acc0 * inv; o.y = acc1 * inv;
            o.z = acc2 * inv; o.w = acc3 * inv;
            *(float4*)(out + (size_t)wid * 32 + c * 4) = o;
        }
    }
}

// ---------------------------------------------------------------------------

extern "C" void kernel_launch(void* const* d_in, const int* in_sizes, int n_in,
                              void* d_out, int out_size, void* d_ws, size_t ws_size,
                              hipStream_t stream) {
    const float* feats = (const float*)d_in[0];
    const int*   src   = (const int*)d_in[1];
    const int*   dst   = (const int*)d_in[2];
    const float* Ws0 = (const float*)d_in[3],  *bs0 = (const float*)d_in[4];
    const float* Wd0 = (const float*)d_in[5],  *bd0 = (const float*)d_in[6];
    const float* a0  = (const float*)d_in[7];
    const float* Ws1 = (const float*)d_in[8],  *bs1 = (const float*)d_in[9];
    const float* Wd1 = (const float*)d_in[10], *bd1 = (const float*)d_in[11];
    const float* a1  = (const float*)d_in[12];
    const float* Ws2 = (const float*)d_in[13], *bs2 = (const float*)d_in[14];
    const float* Wd2 = (const float*)d_in[15], *bd2 = (const float*)d_in[16];
    const float* a2  = (const float*)d_in[17];

    const int N = in_sizes[0] / 128;  // 50000
    const int E = in_sizes[1];        // 800000
    const int nch = (N + 63) / 64;
    const int NPAD = nch * 64;

    char* ws = (char*)d_ws;
    const size_t featB = (size_t)NPAD * 128 * 2;
    unsigned short* xb  = (unsigned short*)(ws);
    unsigned short* hb  = (unsigned short*)(ws + featB);
    unsigned short* fsb = (unsigned short*)(ws + 2 * featB);
    unsigned short* fdb = (unsigned short*)(ws + 3 * featB);
    char* p = ws + 4 * featB;
    unsigned short* wt0 = (unsigned short*)p; p += 256 * 128 * 2;
    unsigned short* wt1 = (unsigned short*)p; p += 256 * 128 * 2;
    unsigned short* wt2 = (unsigned short*)p; p += 64 * 128 * 2;
    int* rowp    = (int*)p;      p += ((size_t)(N + 1) * 4 + 255) / 256 * 256;
    int* binCnt  = (int*)p;      p += (NBIN * 4 + 255) / 256 * 256;
    int* binBase = (int*)p;      p += ((NBIN + 1) * 4 + 255) / 256 * 256;
    int* binCur  = (int*)p;      p += (NBIN * 4 + 255) / 256 * 256;
    unsigned* ebin = (unsigned*)p; p += (size_t)E * 4;
    int* csrc    = (int*)p;

    const int nchunks = (E + CHUNK - 1) / CHUNK;

    // ---- binned CSR build ----
    hipMemsetAsync(binCnt, 0, NBIN * 4, stream);
    bin_count<<<nchunks, 256, 0, stream>>>(dst, binCnt, E);
    bin_scan<<<1, 256, 0, stream>>>(binCnt, binBase, binCur, rowp, N, E);
    bin_scatter<<<nchunks, 256, 0, stream>>>(src, dst, binCur, ebin, E);
    csr_build<<<NBIN, 256, 0, stream>>>(ebin, binBase, rowp, csrc, N);

    // ---- fused bf16 conversions (features + all weight transposes) ----
    const int n4 = N * 128 / 4;
    const int prepTot = n4 + 65536 + 8192;
    prep_all<<<(prepTot + 255) / 256, 256, 0, stream>>>(
        feats, xb, n4, Ws0, Wd0, Ws1, Wd1, Ws2, Wd2, wt0, wt1, wt2);

    const int g256 = nch;
    const int g64  = (nch + 3) / 4;
    const int convGrid = 2048;  // 8192 persistent waves

    // ---- layer 0 ----
    gemm_dual2<256><<<g256, 256, 0, stream>>>(xb, wt0, bs0, bd0, fsb, fdb, N, nch);
    conv128<<<convGrid, 256, 0, stream>>>(fsb, fdb, a0, rowp, csrc, hb, N);
    // ---- layer 1 ----
    gemm_dual2<256><<<g256, 256, 0, stream>>>(hb, wt1, bs1, bd1, fsb, fdb, N, nch);
    conv128<<<convGrid, 256, 0, stream>>>(fsb, fdb, a1, rowp, csrc, hb, N);
    // ---- layer 2 ----
    gemm_dual2<64><<<g64, 256, 0, stream>>>(hb, wt2, bs2, bd2, fsb, fdb, N, nch);
    conv32<<<convGrid, 256, 0, stream>>>(fsb, fdb, a2, rowp, csrc, (float*)d_out, N);
}